// Round 1
// 4905.854 us; speedup vs baseline: 1.6646x; 1.6646x over previous
//
#include <hip/hip_runtime.h>
#include <cstdint>

#define TT 256
#define BB 8
#define NE 64
#define HH 512
#define VOCAB 32000
#define G4 2048
#define RS 32064          // out0 row stride (V + NE)
#define MROWS 2048        // B*T
#define NWG 128
#define LWG 32            // lstm workgroups (sync domain)
#define WSTR 1048         // LDS row stride (halves): 1024 + 24 pad (bank shift 12 dw/row)
#define SCALE 0.044194173824159216f  // 1/sqrt(512)

typedef _Float16 h2 __attribute__((ext_vector_type(2)));
typedef _Float16 h8 __attribute__((ext_vector_type(8)));
typedef float f4 __attribute__((ext_vector_type(4)));

__device__ inline float sigf(float x){ return 1.f/(1.f+__expf(-x)); }

// agent-scope cache-bypassing accessors (sc0 sc1 -> coherent point, no L2 maintenance)
__device__ inline float gload(const float* p){
  return __hip_atomic_load((float*)p, __ATOMIC_RELAXED, __HIP_MEMORY_SCOPE_AGENT);
}
__device__ inline void gstore(float* p, float v){
  __hip_atomic_store(p, v, __ATOMIC_RELAXED, __HIP_MEMORY_SCOPE_AGENT);
}
__device__ inline unsigned long long g64load(const unsigned long long* p){
  return __hip_atomic_load((unsigned long long*)p, __ATOMIC_RELAXED, __HIP_MEMORY_SCOPE_AGENT);
}
__device__ inline void g64store(unsigned long long* p, unsigned long long v){
  __hip_atomic_store(p, v, __ATOMIC_RELAXED, __HIP_MEMORY_SCOPE_AGENT);
}

// ---------------- casts (f32 -> f16, hi or lo residual) ----------------
__global__ __launch_bounds__(256) void cast_k(const float* __restrict__ src, _Float16* __restrict__ dst,
    int total, int src_ld, int src_off, int dst_ld, int dst_off, int cshift, int lo)
{
  int i = blockIdx.x*256 + threadIdx.x;
  if (i >= total) return;
  int c = i & ((1<<cshift)-1);
  int r = i >> cshift;
  float x = src[(long)r*src_ld + src_off + c];
  _Float16 h = (_Float16)x;
  if (lo) h = (_Float16)(x - (float)h);
  dst[(long)r*dst_ld + dst_off + c] = h;
}

__global__ __launch_bounds__(256) void embgather_k(const float* __restrict__ emb,
    const int* __restrict__ outp, _Float16* __restrict__ dst)
{
  int i = blockIdx.x*256 + threadIdx.x;   // < 2048*512, rows m = t*8+b
  int k = i & 511; int m = i >> 9;
  int t = m >> 3, b = m & 7;
  int tok = outp[b*TT + t];
  dst[i] = (_Float16)emb[(long)tok*HH + k];
}

__global__ __launch_bounds__(256) void prep_k(const float* __restrict__ b_ih, const float* __restrict__ b_hh,
    const float* __restrict__ ents, float* bsum, float* hxA, _Float16* hxc16, _Float16* ac16, int* bar)
{
  int i = blockIdx.x*256 + threadIdx.x;   // grid 16 -> 4096 threads
  if (i < G4) bsum[i] = b_ih[i] + b_hh[i];
  if (i < BB*HH) {
    int b = i >> 9, j = i & 511;
    float s = 0.f;
    for (int n = 0; n < NE; n++) s += ents[(size_t)((b<<6)+n)*HH + j];
    s *= (1.0f/NE);                 // cx0 = hx0 = mean over ALL NE entities
    hxA[i]  = s;
    hxc16[i] = (_Float16)s;
    ac16[i]  = (_Float16)0.f;       // a init = 0
  }
  if (i < NWG) bar[i] = 0;
}

// ---------------- f16 MFMA GEMM: C[M,N](f32) = A[M,K] * B[N,K]^T (+bias) ----------------
// All of M,N,K divisible by 128/32. 128x128 tile, 4 waves each 64x64.
__global__ __launch_bounds__(256) void gemm_k(const _Float16* __restrict__ A, const _Float16* __restrict__ Bm,
    float* __restrict__ C, const float* __restrict__ bias,
    int M, int N, int K, int ldc, int accum)
{
  __shared__ __align__(16) _Float16 At[128][40];
  __shared__ __align__(16) _Float16 Bt[128][40];
  int tid = threadIdx.x;
  int n0 = blockIdx.x * 128, m0 = blockIdx.y * 128;
  int wave = tid >> 6, lane = tid & 63;
  int mw = (wave & 1) << 6, nw = (wave >> 1) << 6;
  int lr = tid >> 2, lc = (tid & 3) << 3;
  const _Float16* Ap0 = A + (long)(m0 + lr)*K + lc;
  const _Float16* Ap1 = Ap0 + (long)64*K;
  const _Float16* Bp0 = Bm + (long)(n0 + lr)*K + lc;
  const _Float16* Bp1 = Bp0 + (long)64*K;
  f4 acc[4][4] = {};
  int rr = lane & 15, kq = (lane >> 4) << 3;
  for (int kt = 0; kt < K; kt += 32) {
    h8 av0 = *(const h8*)(Ap0 + kt);
    h8 av1 = *(const h8*)(Ap1 + kt);
    h8 bv0 = *(const h8*)(Bp0 + kt);
    h8 bv1 = *(const h8*)(Bp1 + kt);
    __syncthreads();
    *(h8*)&At[lr][lc]    = av0;
    *(h8*)&At[64+lr][lc] = av1;
    *(h8*)&Bt[lr][lc]    = bv0;
    *(h8*)&Bt[64+lr][lc] = bv1;
    __syncthreads();
    h8 af[4], bf[4];
    #pragma unroll
    for (int mt=0;mt<4;mt++) af[mt] = *(const h8*)&At[mw + mt*16 + rr][kq];
    #pragma unroll
    for (int nt=0;nt<4;nt++) bf[nt] = *(const h8*)&Bt[nw + nt*16 + rr][kq];
    #pragma unroll
    for (int mt=0;mt<4;mt++)
      #pragma unroll
      for (int nt=0;nt<4;nt++)
        acc[mt][nt] = __builtin_amdgcn_mfma_f32_16x16x32_f16(af[mt], bf[nt], acc[mt][nt], 0, 0, 0);
  }
  // C/D layout: col=lane&15, row=(lane>>4)*4+reg  (dtype-independent on gfx950)
  int cc = lane & 15, rq = (lane >> 4) << 2;
  #pragma unroll
  for (int nt=0;nt<4;nt++) {
    int col = n0 + nw + nt*16 + cc;
    float bv = bias ? bias[col] : 0.f;
    #pragma unroll
    for (int mt=0;mt<4;mt++) {
      int row0 = m0 + mw + mt*16 + rq;
      #pragma unroll
      for (int r=0;r<4;r++) {
        long idx = (long)(row0 + r)*ldc + col;
        float v = acc[mt][nt][r] + bv;
        if (accum) C[idx] += v; else C[idx] = v;
      }
    }
  }
}

// ---------------- distributed-flag epoch barrier over 32 slots ----------------
// Data ordering: producers' stores are sc0sc1 (coherent-point); s_waitcnt vmcnt(0)
// + s_barrier before the flag post guarantees they arrived before the flag.
__device__ inline void gpost(int* bar, int wg, int target) {
  asm volatile("s_waitcnt vmcnt(0)" ::: "memory");
  __syncthreads();
  if (threadIdx.x == 0)
    __hip_atomic_store(&bar[wg], target, __ATOMIC_RELAXED, __HIP_MEMORY_SCOPE_AGENT);
}
__device__ inline void gpoll(int* bar, int target) {
  if ((int)threadIdx.x < LWG) {
    while (__hip_atomic_load(&bar[threadIdx.x], __ATOMIC_RELAXED, __HIP_MEMORY_SCOPE_AGENT) < target)
      __builtin_amdgcn_s_sleep(1);
  }
  __syncthreads();
  asm volatile("" ::: "memory");
}
__device__ inline void gbar(int* bar, int wg, int target) {
  gpost(bar, wg, target);
  gpoll(bar, target);
}

// ---------------- persistent LSTM+attention: 32 WGs x 512 threads ----------------
// WG w owns hidden units j in [16w,16w+16) (64 gate rows, weights in LDS) AND
// attention unit (b = w>>2, head = w&3). Per step: 2 global barriers over 32 slots.
__global__ __launch_bounds__(512, 1) void lstm_k(
    const float* __restrict__ gates_pre, const _Float16* __restrict__ Wc,
    const _Float16* __restrict__ Wq, const float* __restrict__ Kb, const float* __restrict__ Vb,
    const int* __restrict__ entlens,
    float* hxf, unsigned long long* hxc, unsigned long long* ac,
    _Float16* l_h, _Float16* l_lo, int* bar)
{
  __shared__ __align__(16) _Float16 wA[64][WSTR];   // 64 gate rows x 1024 (a|hx), 134,144 B
  __shared__ __align__(16) _Float16 act[8][WSTR];   // [b][a(0:512)|hx(512:1024)] f16, 16,768 B
  __shared__ __align__(16) float hxl[512];          // own-b hx fp32 (attention path)
  __shared__ __align__(16) float qv[128];
  __shared__ float sl[64];
  __shared__ __align__(16) float part[4][132];
  __shared__ float fing[8][64];                     // gate sums [b][gate*16+jj]
  __shared__ _Float16 hxh[128];
  __shared__ _Float16 ah[128];
  __shared__ float cxs[128];                        // cell state [b][jj]

  const int tid = threadIdx.x, wg = blockIdx.x;
  const int lane = tid & 63, w = tid >> 6;
  const int b_own = wg >> 2, hid = wg & 3;
  const int el = entlens[b_own];
  const int gb = tid >> 6, gn = tid & 63;                      // (b,n) for gpre/fing
  const int gcol = ((gn >> 4) << 9) + (wg << 4) + (gn & 15);   // gpre column for row n
  const int rr = lane & 15, kq = (lane >> 4) << 3;             // MFMA frag addressing

  // ---- one-time: weights -> LDS, cx init, initial activations ----
  for (int c = tid; c < 8192; c += 512) {                      // 64 rows x 128 h8
    int row = c >> 7, k8 = (c & 127) << 3;
    int gr = ((row >> 4) << 9) + (wg << 4) + (row & 15);       // gate*512 + 16w + jj
    *(h8*)&wA[row][k8] = *(const h8*)(Wc + ((long)gr << 10) + k8);
  }
  if (tid < 128) cxs[tid] = hxf[((tid >> 4) << 9) + (wg << 4) + (tid & 15)];
  {
    unsigned long long a0 = g64load(ac + tid),  a1 = g64load(ac + 512 + tid);
    unsigned long long h0 = g64load(hxc + tid), h1 = g64load(hxc + 512 + tid);
    int bs = tid >> 7, dsx = (tid & 127) << 2;
    *(unsigned long long*)&act[bs][dsx]           = a0;
    *(unsigned long long*)&act[bs + 4][dsx]       = a1;
    *(unsigned long long*)&act[bs][512 + dsx]     = h0;
    *(unsigned long long*)&act[bs + 4][512 + dsx] = h1;
  }
  float gp_reg = gates_pre[((long)gb << 11) + gcol];           // t=0 row = b
  float gpn = 0.f;
  __syncthreads();

  // gates(0): acc = W @ [a0|hx0].  8 waves k-split (64 d each per half).
  // A-frag rows 8-15 duplicate 0-7 (act[rr&7]); their acc rows are discarded.
  f4 acc[4] = {};
  #pragma unroll
  for (int ks = 0; ks < 2; ks++) {
    int d = 512 + (w << 6) + (ks << 5) + kq;
    h8 av = *(const h8*)&act[rr & 7][d];
    #pragma unroll
    for (int nt = 0; nt < 4; nt++) {
      h8 bv = *(const h8*)&wA[(nt << 4) + rr][d];
      acc[nt] = __builtin_amdgcn_mfma_f32_16x16x32_f16(av, bv, acc[nt], 0, 0, 0);
    }
  }
  #pragma unroll
  for (int ks = 0; ks < 2; ks++) {
    int d = (w << 6) + (ks << 5) + kq;
    h8 av = *(const h8*)&act[rr & 7][d];
    #pragma unroll
    for (int nt = 0; nt < 4; nt++) {
      h8 bv = *(const h8*)&wA[(nt << 4) + rr][d];
      acc[nt] = __builtin_amdgcn_mfma_f32_16x16x32_f16(av, bv, acc[nt], 0, 0, 0);
    }
  }

  for (int t = 0; t < TT; t++) {
    // ---- gate reduce: fing = gpre + sum over 8 waves' MFMA partials ----
    fing[gb][gn] = gp_reg;
    __syncthreads();
    if (lane < 32) {            // acc rows 0-7 live in lanes 0-31
      int cc = lane & 15, rq = (lane >> 4) << 2;
      #pragma unroll
      for (int nt = 0; nt < 4; nt++)
        #pragma unroll
        for (int r = 0; r < 4; r++)
          atomicAdd(&fing[rq + r][(nt << 4) + cc], acc[nt][r]);
    }
    __syncthreads();
    // ---- LSTM cell: 8b x 16j ----
    if (tid < 128) {
      int b = tid >> 4, jj = tid & 15;
      float gi = fing[b][jj], gf = fing[b][16+jj], gg = fing[b][32+jj], go = fing[b][48+jj];
      float c_ = sigf(gf)*cxs[tid] + sigf(gi)*tanhf(gg);
      cxs[tid] = c_;
      float h = sigf(go)*tanhf(c_);
      int j = (wg << 4) + jj;
      gstore(hxf + (b << 9) + j, h);         // fp32 hx (attention q path)
      hxh[tid] = (_Float16)h;
      long li = ((long)((b << 8) + t)) << 10;
      _Float16 hh = (_Float16)h;
      l_h[li + j]  = hh;
      l_lo[li + j] = (_Float16)(h - (float)hh);
    }
    __syncthreads();
    if (tid < 32) {                          // pack fp16 hx -> 8B comm words
      int b = tid >> 2, q4 = tid & 3;
      union { _Float16 hv[4]; unsigned long long u; } pk;
      #pragma unroll
      for (int z = 0; z < 4; z++) pk.hv[z] = hxh[(b << 4) + (q4 << 2) + z];
      g64store(hxc + (b << 7) + (wg << 2) + q4, pk.u);
    }
    // ---- barrier 1: hx[t] globally visible ----
    gbar(bar, wg, 2*t + 1);
    // ---- stage hx (all b, fp16) + own-b fp32 + prefetch gpre(t+1) ----
    {
      unsigned long long h0 = g64load(hxc + tid), h1 = g64load(hxc + 512 + tid);
      int tn = (t < TT-1) ? t+1 : TT-1;
      gpn = gates_pre[((long)((tn << 3) + gb) << 11) + gcol];
      float hv = gload(hxf + (b_own << 9) + tid);
      int bs = tid >> 7, dsx = (tid & 127) << 2;
      *(unsigned long long*)&act[bs][512 + dsx]     = h0;
      *(unsigned long long*)&act[bs + 4][512 + dsx] = h1;
      hxl[tid] = hv;
    }
    __syncthreads();
    // ---- attention q: 4 threads per output dim ----
    {
      int qd = tid >> 2, qq = tid & 3;
      const _Float16* wq = Wq + (((long)((hid << 7) + qd)) << 9) + (qq << 7);
      const float* hp = hxl + (qq << 7);
      float s = 0.f;
      #pragma unroll
      for (int k = 0; k < 128; k += 8) {
        h8 wv8 = *(const h8*)(wq + k);
        #pragma unroll
        for (int j2 = 0; j2 < 8; j2++) s += (float)wv8[j2] * hp[k + j2];
      }
      s += __shfl_xor(s, 1); s += __shfl_xor(s, 2);
      if (qq == 0) qv[qd] = s;
    }
    __syncthreads();
    // ---- scores: 8 threads per entity ----
    {
      int n = tid >> 3, oct = tid & 7;
      const float* kp = Kb + (((long)((b_own << 6) + n)) << 9) + (hid << 7) + (oct << 4);
      const float* qp = qv + (oct << 4);
      float s = 0.f;
      #pragma unroll
      for (int d = 0; d < 16; d++) s += qp[d] * kp[d];
      s += __shfl_xor(s, 1); s += __shfl_xor(s, 2); s += __shfl_xor(s, 4);
      if (oct == 0) {
        s *= SCALE;
        if (n > el) s = -1e30f;
        sl[n] = s;
      }
    }
    __syncthreads();
    if (tid < 64) {                          // softmax over 64 entities, one wave
      float x = sl[tid], mx = x;
      #pragma unroll
      for (int off = 32; off > 0; off >>= 1) mx = fmaxf(mx, __shfl_xor(mx, off));
      float e = __expf(x - mx), sm = e;
      #pragma unroll
      for (int off = 32; off > 0; off >>= 1) sm += __shfl_xor(sm, off);
      sl[tid] = e / sm;
    }
    __syncthreads();
    // ---- AV: 4-way n-split x 128 d ----
    {
      int d = tid & 127, g = tid >> 7;
      const float* vp = Vb + (((long)((b_own << 6) + (g << 4))) << 9) + (hid << 7) + d;
      float s = 0.f;
      #pragma unroll
      for (int i2 = 0; i2 < 16; i2++) s += sl[(g << 4) + i2] * vp[(long)i2 << 9];
      part[g][d] = s;
    }
    __syncthreads();
    if (tid < 128) {
      float a_ = part[0][tid] + part[1][tid] + part[2][tid] + part[3][tid];
      long li = (((long)((b_own << 8) + t)) << 10) + 512 + (hid << 7) + tid;
      _Float16 hh = (_Float16)a_;
      l_h[li]  = hh;
      l_lo[li] = (_Float16)(a_ - (float)hh);
      ah[tid] = hh;
    }
    __syncthreads();
    if (t == TT - 1) break;                  // a[255] l-stores done; nothing else needed
    if (tid < 32) {                          // pack fp16 a -> comm
      union { _Float16 hv[4]; unsigned long long u; } pk;
      #pragma unroll
      for (int z = 0; z < 4; z++) pk.hv[z] = ah[(tid << 2) + z];
      g64store(ac + (b_own << 7) + (hid << 5) + tid, pk.u);
    }
    // ---- post bar2, overlap hx-half of gates(t+1), then poll ----
    gpost(bar, wg, 2*t + 2);
    {
      #pragma unroll
      for (int nt = 0; nt < 4; nt++) { f4 z = {}; acc[nt] = z; }
      #pragma unroll
      for (int ks = 0; ks < 2; ks++) {
        int d = 512 + (w << 6) + (ks << 5) + kq;
        h8 av = *(const h8*)&act[rr & 7][d];
        #pragma unroll
        for (int nt = 0; nt < 4; nt++) {
          h8 bv = *(const h8*)&wA[(nt << 4) + rr][d];
          acc[nt] = __builtin_amdgcn_mfma_f32_16x16x32_f16(av, bv, acc[nt], 0, 0, 0);
        }
      }
    }
    gpoll(bar, 2*t + 2);
    // ---- stage a[t], a-half of gates(t+1) ----
    {
      unsigned long long a0 = g64load(ac + tid), a1 = g64load(ac + 512 + tid);
      int bs = tid >> 7, dsx = (tid & 127) << 2;
      *(unsigned long long*)&act[bs][dsx]     = a0;
      *(unsigned long long*)&act[bs + 4][dsx] = a1;
    }
    __syncthreads();
    {
      #pragma unroll
      for (int ks = 0; ks < 2; ks++) {
        int d = (w << 6) + (ks << 5) + kq;
        h8 av = *(const h8*)&act[rr & 7][d];
        #pragma unroll
        for (int nt = 0; nt < 4; nt++) {
          h8 bv = *(const h8*)&wA[(nt << 4) + rr][d];
          acc[nt] = __builtin_amdgcn_mfma_f32_16x16x32_f16(av, bv, acc[nt], 0, 0, 0);
        }
      }
    }
    gp_reg = gpn;
  }
}

// ---------------- online softmax stats over V + sigmoid switch gate ----------------
__global__ __launch_bounds__(256) void stats_k(const float* __restrict__ out0,
    const _Float16* __restrict__ l_h, const float* __restrict__ swW, const float* __restrict__ swb,
    float* rowmax, float* rowsum, float* sgate)
{
  int m = blockIdx.x, tid = threadIdx.x;
  const float* row = out0 + (long)m*RS;
  float mx = -1e30f, sm = 0.f;
  for (int c = tid; c < VOCAB; c += 256) {
    float x = row[c];
    float nm = fmaxf(mx, x);
    sm = sm*__expf(mx-nm) + __expf(x-nm);
    mx = nm;
  }
  float sd = 0.f;
  const _Float16* lr_ = l_h + ((long)m << 10);
  for (int k = tid; k < 1024; k += 256) sd += (float)lr_[k] * swW[k];
  #pragma unroll
  for (int off=32; off>0; off>>=1) {
    float omx = __shfl_xor(mx, off), osm = __shfl_xor(sm, off);
    float nm = fmaxf(mx, omx);
    sm = sm*__expf(mx-nm) + osm*__expf(omx-nm);
    mx = nm;
    sd += __shfl_xor(sd, off);
  }
  __shared__ float smx[4], ssm[4], ssd[4];
  int wv = tid >> 6;
  if ((tid & 63) == 0) { smx[wv]=mx; ssm[wv]=sm; ssd[wv]=sd; }
  __syncthreads();
  if (tid == 0) {
    float M = smx[0], S = ssm[0], D = ssd[0];
    for (int w2=1;w2<4;w2++) {
      float nm = fmaxf(M, smx[w2]);
      S = S*__expf(M-nm) + ssm[w2]*__expf(smx[w2]-nm);
      M = nm; D += ssd[w2];
    }
    rowmax[m] = M; rowsum[m] = S;
    sgate[m] = 1.f/(1.f + __expf(-(D + swb[0])));
  }
}

// ---------------- finalize: log(softmax*s + 1e-6) over V, pointer softmax z over NE ----------------
__global__ __launch_bounds__(256) void fin_k(float* __restrict__ out,
    const float* __restrict__ dec, const float* __restrict__ ents, const int* __restrict__ entlens,
    const float* __restrict__ rowmax, const float* __restrict__ rowsum, const float* __restrict__ sgate)
{
  int m = blockIdx.x, tid = threadIdx.x;
  int b = m >> 8;
  __shared__ float dl[512];
  for (int i = tid; i < 512; i += 256) dl[i] = dec[((long)m<<9) + i];
  __syncthreads();
  float s = sgate[m];
  if (tid < 64) {
    int n = tid;
    const float* ep = ents + (((long)((b<<6)+n)) << 9);
    float uq = 0.f;
    for (int k=0;k<512;k+=4)
      uq += dl[k]*ep[k] + dl[k+1]*ep[k+1] + dl[k+2]*ep[k+2] + dl[k+3]*ep[k+3];
    if (n > entlens[b]) uq = -1e30f;
    float mx = uq;
    #pragma unroll
    for (int off=32; off>0; off>>=1) mx = fmaxf(mx, __shfl_xor(mx, off));
    float e = __expf(uq - mx);
    float sum = e;
    #pragma unroll
    for (int off=32; off>0; off>>=1) sum += __shfl_xor(sum, off);
    float z = (e/sum) * (1.f - s);
    out[(long)m*RS + VOCAB + n] = __logf(z + 1e-6f);
    out[(long)MROWS*RS + ((long)m<<6) + n] = z;     // output 1
  }
  float mx = rowmax[m], inv = 1.f/rowsum[m];
  for (int c = tid; c < VOCAB; c += 256) {
    long idx = (long)m*RS + c;
    float x = out[idx];
    out[idx] = __logf(__expf(x - mx)*inv*s + 1e-6f);
  }
}

// ---------------- launch ----------------
extern "C" void kernel_launch(void* const* d_in, const int* in_sizes, int n_in,
                              void* d_out, int out_size, void* d_ws, size_t ws_size,
                              hipStream_t stream)
{
  const int*   outp    = (const int*)d_in[0];
  const float* ents    = (const float*)d_in[1];
  const int*   entlens = (const int*)d_in[2];
  const float* emb     = (const float*)d_in[3];
  const float* W_ih    = (const float*)d_in[4];
  const float* W_hh    = (const float*)d_in[5];
  const float* b_ih    = (const float*)d_in[6];
  const float* b_hh    = (const float*)d_in[7];
  const float* Wq      = (const float*)d_in[8];
  const float* Wk      = (const float*)d_in[9];
  const float* Wv      = (const float*)d_in[10];
  const float* out_W   = (const float*)d_in[11];
  const float* out_b   = (const float*)d_in[12];
  const float* sw_W    = (const float*)d_in[13];
  const float* sw_b    = (const float*)d_in[14];
  const float* mattn_W = (const float*)d_in[15];
  const float* mattn_b = (const float*)d_in[16];
  float* out = (float*)d_out;
  (void)in_sizes; (void)n_in; (void)out_size; (void)ws_size;

  char* w = (char*)d_ws;
  size_t off = 0;
  auto alloc = [&](size_t bytes) -> char* {
    char* p = w + off; off += bytes; off = (off + 255) & ~(size_t)255; return p;
  };
  _Float16* outW_h = (_Float16*)alloc((size_t)VOCAB*1024*2);
  _Float16* l_h    = (_Float16*)alloc((size_t)MROWS*1024*2);
  _Float16* l_lo   = (_Float16*)alloc((size_t)MROWS*1024*2);
  float*    gpre   = (float*)alloc((size_t)MROWS*2048*4);
  _Float16* Wc_h   = (_Float16*)alloc((size_t)2048*1024*2);
  _Float16* Wihk_h = (_Float16*)alloc((size_t)2048*512*2);
  _Float16* emb_h  = (_Float16*)alloc((size_t)2048*512*2);
  _Float16* ents_h = (_Float16*)alloc((size_t)512*512*2);
  _Float16* Wk_h   = (_Float16*)alloc((size_t)512*512*2);
  _Float16* Wv_h   = (_Float16*)alloc((size_t)512*512*2);
  _Float16* Wq_h   = (_Float16*)alloc((size_t)512*512*2);
  _Float16* mat_h  = (_Float16*)alloc((size_t)512*1024*2);
  _Float16* mat_lo = (_Float16*)alloc((size_t)512*1024*2);
  float*    Kb     = (float*)alloc((size_t)512*512*4);
  float*    Vb     = (float*)alloc((size_t)512*512*4);
  float*    dec    = (float*)alloc((size_t)MROWS*512*4);
  float*    bsum   = (float*)alloc(2048*4);
  float*    hxA    = (float*)alloc(8*512*4);
  unsigned long long* hxc = (unsigned long long*)alloc(8*512*2);   // fp16 comm, 8KB
  unsigned long long* acb = (unsigned long long*)alloc(8*512*2);   // fp16 comm, 8KB
  float*    rmax   = (float*)alloc(2048*4);
  float*    rsum   = (float*)alloc(2048*4);
  float*    sg     = (float*)alloc(2048*4);
  int*      bar    = (int*)alloc(1024);

  auto cast = [&](const float* s, _Float16* d, int total, int sld, int soff, int dld, int doff, int cs, int lo) {
    cast_k<<<(total+255)/256, 256, 0, stream>>>(s, d, total, sld, soff, dld, doff, cs, lo);
  };
  cast(out_W,   outW_h, VOCAB*1024, 1024, 0,   1024, 0,   10, 0);
  cast(W_ih,    Wihk_h, 2048*512,   1024, 512, 512,  0,   9,  0);
  cast(W_ih,    Wc_h,   2048*512,   1024, 0,   1024, 0,   9,  0);
  cast(W_hh,    Wc_h,   2048*512,   512,  0,   1024, 512, 9,  0);
  cast(Wq,      Wq_h,   512*512,    512,  0,   512,  0,   9,  0);
  cast(Wk,      Wk_h,   512*512,    512,  0,   512,  0,   9,  0);
  cast(Wv,      Wv_h,   512*512,    512,  0,   512,  0,   9,  0);
  cast(mattn_W, mat_h,  512*1024,   1024, 0,   1024, 0,   10, 0);
  cast(mattn_W, mat_lo, 512*1024,   1024, 0,   1024, 0,   10, 1);
  cast(ents,    ents_h, 512*512,    512,  0,   512,  0,   9,  0);

  embgather_k<<<4096, 256, 0, stream>>>(emb, outp, emb_h);
  prep_k<<<16, 256, 0, stream>>>(b_ih, b_hh, ents, bsum, hxA, (_Float16*)hxc, (_Float16*)acb, bar);

  gemm_k<<<dim3(4,4),   256, 0, stream>>>(ents_h, Wk_h,   Kb,   nullptr, 512,  512,   512,  512,  0);
  gemm_k<<<dim3(4,4),   256, 0, stream>>>(ents_h, Wv_h,   Vb,   nullptr, 512,  512,   512,  512,  0);
  gemm_k<<<dim3(16,16), 256, 0, stream>>>(emb_h,  Wihk_h, gpre, bsum,    2048, 2048,  512,  2048, 0);

  lstm_k<<<LWG, 512, 0, stream>>>(gpre, Wc_h, Wq_h, Kb, Vb, entlens,
                                  hxA, hxc, acb, l_h, l_lo, bar);

  gemm_k<<<dim3(4,16),   256, 0, stream>>>(l_h,  mat_h,  dec, mattn_b, 2048, 512,   1024, 512, 0);
  gemm_k<<<dim3(4,16),   256, 0, stream>>>(l_lo, mat_h,  dec, nullptr, 2048, 512,   1024, 512, 1);
  gemm_k<<<dim3(4,16),   256, 0, stream>>>(l_h,  mat_lo, dec, nullptr, 2048, 512,   1024, 512, 1);
  gemm_k<<<dim3(250,16), 256, 0, stream>>>(l_h,  outW_h, out, out_b,   2048, 32000, 1024, RS,  0);

  stats_k<<<2048, 256, 0, stream>>>(out, l_h, sw_W, sw_b, rmax, rsum, sg);
  fin_k<<<2048, 256, 0, stream>>>(out, dec, ents, entlens, rmax, rsum, sg);
}